// Round 10
// baseline (222.681 us; speedup 1.0000x reference)
//
#include <hip/hip_runtime.h>

typedef unsigned short u16;
typedef unsigned int u32;

#define BB 16
#define NN 4096
#define MM 1024
#define C1V 128
#define C2V 256
#define EPSV 1e-5f
#define INV_CNT (1.0f/65536.0f)
#define NREP 32  // stats atomic replicas

typedef __attribute__((ext_vector_type(8))) short bf16x8;
typedef __attribute__((ext_vector_type(4))) float f32x4;

static __device__ __forceinline__ u16 f2b(float f) {
  u32 u = __float_as_uint(f);
  u32 r = (u + 0x7FFFu + ((u >> 16) & 1u)) >> 16;
  return (u16)r;
}
static __device__ __forceinline__ float b2f(u16 s) {
  return __uint_as_float(((u32)s) << 16);
}

#define GLD_LDS16(gp, lp)                                                      \
  __builtin_amdgcn_global_load_lds(                                            \
      (const __attribute__((address_space(1))) void*)(gp),                     \
      (__attribute__((address_space(3))) void*)(lp), 16, 0, 0)

// ---------------------------------------------------------------------------
// Mega-prep kernel.
//   blocks [0,1024)       : 3-NN partials, 1 query/thread (256-eval chains;
//                           bit-identical pd/pi vs the 2-query variant)
//   blocks [1024,1664)    : W1/W2 fp32->bf16 cast
//   blocks [1664,1696)    : zero the 128KB stats replica region
//   blocks [1696,3744)    : transpose-cast points2 -> p2t (64c x 32p tiles)
//   blocks [3744,7840)    : transpose-cast points1 -> p1t (64c x 32p tiles)
// NOTE (journal): do NOT replace the cndmask running-min chains with
// __builtin_amdgcn_fmed3f — two rounds failed correctness that way (R6/R7).
// ---------------------------------------------------------------------------
__device__ __forceinline__ void tcast_tile64(const float* __restrict__ in,
                                             u16* __restrict__ out, int C,
                                             int P, int p0, int c0, int b,
                                             float (*tile)[33]) {
  int tx = threadIdx.x & 31, ty = threadIdx.x >> 5;
  const float* ib = in + (size_t)b * C * P;
  u16* ob = out + (size_t)b * P * C;
#pragma unroll
  for (int i = 0; i < 8; ++i)
    tile[ty + i * 8][tx] = ib[(size_t)(c0 + ty + i * 8) * P + p0 + tx];
  __syncthreads();
#pragma unroll
  for (int i = 0; i < 4; ++i) {
    int p = ty + i * 8;
    u32 v = (u32)f2b(tile[tx * 2][p]) | ((u32)f2b(tile[tx * 2 + 1][p]) << 16);
    *(u32*)&ob[(size_t)(p0 + p) * C + c0 + tx * 2] = v;
  }
}

__global__ __launch_bounds__(256) void prep_kernel(
    const float* __restrict__ xyz1, const float* __restrict__ xyz2,
    float* __restrict__ pd, int* __restrict__ pi,
    const float* __restrict__ points1, const float* __restrict__ points2,
    u16* __restrict__ p1t, u16* __restrict__ p2t,
    const float* __restrict__ W1, const float* __restrict__ W2,
    u16* __restrict__ W1b, u16* __restrict__ W2b,
    float* __restrict__ statsZero) {
  __shared__ float4 cand[256];
  __shared__ float tile[64][33];
  int bx = blockIdx.x;
  int t = threadIdx.x;

  if (bx < 1024) {
    // ---- 3-NN partials: block = (batch b, qtile of 256, chunk c) ----
    int c = bx & 3;
    int qt = (bx >> 2) & 15;
    int b = bx >> 6;
    const float* x2b = xyz2 + b * 3 * MM;
    {
      float x = x2b[c * 256 + t];
      float y = x2b[MM + c * 256 + t];
      float z = x2b[2 * MM + c * 256 + t];
      cand[t] = make_float4(x, y, z, x * x + y * y + z * z);
    }
    __syncthreads();
    const float* x1b = xyz1 + b * 3 * NN;
    int n = qt * 256 + t;
    float px = x1b[n], py = x1b[NN + n], pz = x1b[2 * NN + n];
    const float INF = 3.4e38f;
    float k0 = INF, k1 = INF, k2 = INF;
    int j0 = 0, j1 = 0, j2 = 0;
#pragma unroll 8
    for (int m = 0; m < 256; ++m) {
      float4 cd = cand[m];
      float dot = fmaf(px, cd.x, fmaf(py, cd.y, pz * cd.z));
      float key = fmaf(-2.0f, dot, cd.w);
      bool c0 = key < k0, c1 = key < k1, c2 = key < k2;
      k2 = c1 ? k1 : (c2 ? key : k2);
      j2 = c1 ? j1 : (c2 ? m : j2);
      k1 = c0 ? k0 : (c1 ? key : k1);
      j1 = c0 ? j0 : (c1 ? m : j1);
      k0 = c0 ? key : k0;
      j0 = c0 ? m : j0;
    }
    float pn = px * px + py * py + pz * pz;
    int gq = b * NN + n;
    int base = c << 8;
    ((float4*)pd)[(size_t)c * 65536 + gq] =
        make_float4(fmaxf(k0 + pn, 1e-10f), fmaxf(k1 + pn, 1e-10f),
                    fmaxf(k2 + pn, 1e-10f), 0.0f);
    ((int4*)pi)[(size_t)c * 65536 + gq] =
        make_int4(base + j0, base + j1, base + j2, 0);
  } else if (bx < 1664) {
    // ---- weight casts ----
    int i = (bx - 1024) * 256 + t;
    if (i < 98304) W1b[i] = f2b(W1[i]);
    else if (i < 163840) W2b[i - 98304] = f2b(W2[i - 98304]);
  } else if (bx < 1696) {
    // ---- zero stats replicas: 32 blocks x 256 threads x 16B = 131072 B ----
    ((float4*)statsZero)[(bx - 1664) * 256 + t] =
        make_float4(0.f, 0.f, 0.f, 0.f);
  } else if (bx < 3744) {
    // ---- points2 transpose-cast: P=1024 (32 ptiles), C=256 (4 ctiles) ----
    int local = bx - 1696;
    int pt = local & 31, ct = (local >> 5) & 3, b = local >> 7;
    tcast_tile64(points2, p2t, C2V, MM, pt * 32, ct * 64, b, tile);
  } else {
    // ---- points1 transpose-cast: P=4096 (128 ptiles), C=128 (2 ctiles) ----
    int local = bx - 3744;
    int pt = local & 127, ct = (local >> 7) & 1, b = local >> 8;
    tcast_tile64(points1, p1t, C1V, NN, pt * 32, ct * 64, b, tile);
  }
}

// ---------------------------------------------------------------------------
// MFMA GEMM (G pass only): 128x128 tile, 4 waves 2x2, 4x4 mfma.
//   NTILES>0: XCD-aware row-swizzle. OUTB: bf16 store via LDS bounce.
// ---------------------------------------------------------------------------
template <int K, int NTILES, bool OUTB>
__global__ __launch_bounds__(256) void gemm_mfma(
    const u16* __restrict__ A, int lda, const u16* __restrict__ B, int ldb,
    void* __restrict__ out) {
  __shared__ u16 smem[16384];
  int t = threadIdx.x;
  int w = t >> 6, l = t & 63;
  int n0;
  if (NTILES > 0) {
    int p = blockIdx.x;
    int batch = ((p & 7) << 1) | ((p >> 3) & 1);
    int nt = p >> 4;
    n0 = (batch * NTILES + nt) * 128;
  } else {
    n0 = blockIdx.x * 128;
  }
  int o0 = blockIdx.y * 128;

  int wm = w & 1, wn = w >> 1;
  int lr = l >> 2, lc = l & 3;
  int q = l >> 4, m = l & 15;

  f32x4 acc[4][4] = {};
  u16* As = smem;
  u16* Bs = smem + 4096;

  const u16* arow = A + (size_t)n0 * lda;
  const u16* brow = B + (size_t)o0 * ldb;

#pragma unroll
  for (int kt = 0; kt < K; kt += 32) {
    __syncthreads();
#pragma unroll
    for (int r = 0; r < 2; ++r) {
      int row = r * 64 + w * 16 + lr;
      GLD_LDS16(arow + (size_t)row * lda + kt + lc * 8, As + row * 32 + lc * 8);
    }
#pragma unroll
    for (int r = 0; r < 2; ++r) {
      int row = r * 64 + w * 16 + lr;
      GLD_LDS16(brow + (size_t)row * ldb + kt + lc * 8, Bs + row * 32 + lc * 8);
    }
    __syncthreads();
    bf16x8 af[4], bf[4];
#pragma unroll
    for (int i = 0; i < 4; ++i)
      af[i] = *(const bf16x8*)(As + (wm * 64 + i * 16 + m) * 32 + q * 8);
#pragma unroll
    for (int j = 0; j < 4; ++j)
      bf[j] = *(const bf16x8*)(Bs + (wn * 64 + j * 16 + m) * 32 + q * 8);
#pragma unroll
    for (int i = 0; i < 4; ++i)
#pragma unroll
      for (int j = 0; j < 4; ++j)
        acc[i][j] =
            __builtin_amdgcn_mfma_f32_16x16x32_bf16(af[i], bf[j], acc[i][j], 0, 0, 0);
  }

  if (OUTB) {
    __syncthreads();
#pragma unroll
    for (int i = 0; i < 4; ++i)
#pragma unroll
      for (int reg = 0; reg < 4; ++reg) {
        int row = wm * 64 + i * 16 + q * 4 + reg;
#pragma unroll
        for (int j = 0; j < 4; ++j)
          smem[row * 128 + wn * 64 + j * 16 + m] = f2b(acc[i][j][reg]);
      }
    __syncthreads();
    u16* outp = (u16*)out;
    int rbase = w * 32 + (l >> 4);
    int seg = l & 15;
#pragma unroll
    for (int itr = 0; itr < 8; ++itr) {
      int row = rbase + itr * 4;
      uint4 v = *(const uint4*)(smem + row * 128 + seg * 8);
      *(uint4*)(outp + (size_t)(n0 + row) * 256 + o0 + seg * 8) = v;
    }
  } else {
#pragma unroll
    for (int i = 0; i < 4; ++i) {
      int gr = n0 + wm * 64 + i * 16 + q * 4;
#pragma unroll
      for (int reg = 0; reg < 4; ++reg)
#pragma unroll
        for (int j = 0; j < 4; ++j) {
          int gc = o0 + wn * 64 + j * 16 + m;
          ((float*)out)[(size_t)(gr + reg) * 256 + gc] = acc[i][j][reg];
        }
    }
  }
}

// ---------------------------------------------------------------------------
// gemm1_32: h1 = p1t * W1[:,256:384]^T + interp(G), 32x256 tile, grid 2048.
//   Occupancy-first: single-buffered LDS ~19KB -> 8 blocks/CU (32 waves/CU),
//   doubling TLP vs the 64-row/2-phase version (which was latency-bound at
//   OccupancyPercent ~17%). acc[2][4], 8 MFMA/wave/iter.
//   XCD swizzle bijective (2048 % 8 == 0).
// ---------------------------------------------------------------------------
__global__ __launch_bounds__(256) void gemm1_32(
    const u16* __restrict__ A, const u16* __restrict__ B,
    u16* __restrict__ out, const u16* __restrict__ G,
    const float* __restrict__ pd, const int* __restrict__ pi,
    float* __restrict__ statsOut) {
  __shared__ __align__(16) u16 smem[9216];  // As[32][32] 2KB | Bs[256][32] 16KB
  __shared__ float wsh[32][3];
  __shared__ int ish[32][3];
  int t = threadIdx.x;
  int w = t >> 6, l = t & 63;
  int p = blockIdx.x;
  int batch = ((p & 7) << 1) | ((p >> 3) & 1);
  int nt = p >> 4;                  // 0..127
  int n0 = batch * NN + nt * 32;    // global row

  // ---- 3-NN merge preamble (once per row) ----
  if (t < 32) {
    int gq = n0 + t;
    float4 d0 = ((const float4*)pd)[gq];
    int4 ii0 = ((const int4*)pi)[gq];
    float a0 = d0.x, a1 = d0.y, a2 = d0.z;
    int b0 = ii0.x, b1 = ii0.y, b2 = ii0.z;
#pragma unroll
    for (int c = 1; c < 4; ++c) {
      float4 dc = ((const float4*)pd)[(size_t)c * 65536 + gq];
      int4 ic = ((const int4*)pi)[(size_t)c * 65536 + gq];
      float kv[3] = {dc.x, dc.y, dc.z};
      int jv[3] = {ic.x, ic.y, ic.z};
#pragma unroll
      for (int j = 0; j < 3; ++j) {
        float key = kv[j];
        int idx = jv[j];
        bool c0 = key < a0, c1 = key < a1, c2 = key < a2;
        a2 = c1 ? a1 : (c2 ? key : a2);
        b2 = c1 ? b1 : (c2 ? idx : b2);
        a1 = c0 ? a0 : (c1 ? key : a1);
        b1 = c0 ? b0 : (c1 ? idx : b1);
        a0 = c0 ? key : a0;
        b0 = c0 ? idx : b0;
      }
    }
    float v0 = 1.0f / a0, v1 = 1.0f / a1, v2 = 1.0f / a2;
    float s = 1.0f / (v0 + v1 + v2);
    wsh[t][0] = v0 * s; wsh[t][1] = v1 * s; wsh[t][2] = v2 * s;
    ish[t][0] = b0;     ish[t][1] = b1;     ish[t][2] = b2;
  }

  int q = l >> 4, m = l & 15;   // mfma lane decomposition
  int sr = l >> 2, lc = l & 3;  // staging: row-in-16, 16B chunk

  f32x4 acc[2][4] = {};
  u16* As = smem;          // [32][32]
  u16* Bs = smem + 1024;   // [256][32]
  const u16* arow = A + (size_t)n0 * 128;

#pragma unroll
  for (int kt = 0; kt < 128; kt += 32) {
    __syncthreads();
    if (w < 2) {
      int row = w * 16 + sr;  // 0..31
      GLD_LDS16(arow + (size_t)row * 128 + kt + lc * 8, As + row * 32 + lc * 8);
    }
#pragma unroll
    for (int r = 0; r < 4; ++r) {
      int row = r * 64 + w * 16 + sr;  // 0..255 output channels
      GLD_LDS16(B + (size_t)row * 384 + kt + lc * 8, Bs + row * 32 + lc * 8);
    }
    __syncthreads();
    bf16x8 af[2], bf[4];
#pragma unroll
    for (int i = 0; i < 2; ++i)
      af[i] = *(const bf16x8*)(As + (i * 16 + m) * 32 + q * 8);
#pragma unroll
    for (int j = 0; j < 4; ++j)
      bf[j] = *(const bf16x8*)(Bs + (w * 64 + j * 16 + m) * 32 + q * 8);
#pragma unroll
    for (int i = 0; i < 2; ++i)
#pragma unroll
      for (int j = 0; j < 4; ++j)
        acc[i][j] =
            __builtin_amdgcn_mfma_f32_16x16x32_bf16(af[i], bf[j], acc[i][j], 0, 0, 0);
  }

  // ---- interp gather -> swizzled 32x256 LDS tile -> acc add ----
  __syncthreads();  // As/Bs dead; reuse smem[0..8192) as 32x256 tile
  {
    int b = n0 >> 12;
    int rl = t >> 3, oc = t & 7;  // row (0..31), col-octant (32 cols)
    float w0 = wsh[rl][0], w1 = wsh[rl][1], w2 = wsh[rl][2];
    const u16* g0 = G + ((size_t)(b * 1024 + ish[rl][0])) * 256 + oc * 32;
    const u16* g1 = G + ((size_t)(b * 1024 + ish[rl][1])) * 256 + oc * 32;
    const u16* g2 = G + ((size_t)(b * 1024 + ish[rl][2])) * 256 + oc * 32;
    int r3 = rl & 7;  // row&7 swizzle: dense-optimal write banks
#pragma unroll
    for (int c8 = 0; c8 < 4; ++c8) {
      bf16x8 v0 = *(const bf16x8*)(g0 + c8 * 8);
      bf16x8 v1 = *(const bf16x8*)(g1 + c8 * 8);
      bf16x8 v2 = *(const bf16x8*)(g2 + c8 * 8);
      union { uint4 u; u16 s[8]; } o;
#pragma unroll
      for (int e = 0; e < 8; ++e) {
        float f = w0 * b2f((u16)v0[e]) + w1 * b2f((u16)v1[e]) +
                  w2 * b2f((u16)v2[e]);
        o.s[e] = f2b(f);
      }
      int ch = (oc * 4 + c8) ^ r3;  // XOR swizzle (32 chunks/row)
      *(uint4*)(smem + rl * 256 + ch * 8) = o.u;
    }
  }
  __syncthreads();
#pragma unroll
  for (int i = 0; i < 2; ++i)
#pragma unroll
    for (int reg = 0; reg < 4; ++reg) {
      int row = i * 16 + q * 4 + reg;
      int rx = row & 7;
#pragma unroll
      for (int j = 0; j < 4; ++j) {
        int col = w * 64 + j * 16 + m;
        int off = row * 256 + (((col >> 3) ^ rx) << 3) + (col & 7);
        acc[i][j][reg] += b2f(smem[off]);
      }
    }

  // ---- stats1 per-column sum/sumsq atomics ----
  {
    int rep = blockIdx.x & (NREP - 1);
#pragma unroll
    for (int j = 0; j < 4; ++j) {
      float s = 0.0f, ss = 0.0f;
#pragma unroll
      for (int i = 0; i < 2; ++i)
#pragma unroll
        for (int reg = 0; reg < 4; ++reg) {
          float v = acc[i][j][reg];
          s += v;
          ss += v * v;
        }
      s += __shfl_down(s, 32); ss += __shfl_down(ss, 32);
      s += __shfl_down(s, 16); ss += __shfl_down(ss, 16);
      if (l < 16) {
        int c = w * 64 + j * 16 + l;
        atomicAdd(&statsOut[rep * 512 + c], s);
        atomicAdd(&statsOut[rep * 512 + 256 + c], ss);
      }
    }
  }

  // ---- bf16 store via 32x256 LDS bounce ----
  __syncthreads();
#pragma unroll
  for (int i = 0; i < 2; ++i)
#pragma unroll
    for (int reg = 0; reg < 4; ++reg) {
      int row = i * 16 + q * 4 + reg;
#pragma unroll
      for (int j = 0; j < 4; ++j)
        smem[row * 256 + w * 64 + j * 16 + m] = f2b(acc[i][j][reg]);
    }
  __syncthreads();
  int rbase = t >> 5, seg = t & 31;
#pragma unroll
  for (int itr = 0; itr < 4; ++itr) {
    int row = rbase + itr * 8;
    uint4 v = *(const uint4*)(smem + row * 256 + seg * 8);
    *(uint4*)(out + (size_t)(n0 + row) * 256 + seg * 8) = v;
  }
}

// ---------------------------------------------------------------------------
// gemm2_32: h2 = relu(BN1(h1)) * W2^T, 32x256 tile, grid 2048.
//   LDS exactly 20480B (As 2K + Bs 16K + scA/shA 2K) -> 8 blocks/CU.
// ---------------------------------------------------------------------------
__global__ __launch_bounds__(256) void gemm2_32(
    const u16* __restrict__ A, const u16* __restrict__ B,
    u16* __restrict__ out, float* __restrict__ statsOut,
    const float* __restrict__ statsInR, const float* __restrict__ gamma,
    const float* __restrict__ beta) {
  __shared__ __align__(16) u16 smem[9216];  // As[32][32] | Bs[256][32]
  __shared__ float scA[256], shA[256];
  int t = threadIdx.x;
  int w = t >> 6, l = t & 63;
  int n0 = blockIdx.x * 32;

  // BN1 scale/shift from stats1 replicas (plain cached loads)
  {
    float s = 0.0f, qq = 0.0f;
#pragma unroll
    for (int r = 0; r < NREP; ++r) {
      s += statsInR[r * 512 + t];
      qq += statsInR[r * 512 + 256 + t];
    }
    float mean = s * INV_CNT;
    float var = qq * INV_CNT - mean * mean;
    float sc = rsqrtf(var + EPSV) * gamma[t];
    scA[t] = sc;
    shA[t] = beta[t] - mean * sc;
  }

  int q = l >> 4, m = l & 15;   // mfma lane decomposition
  int sr = l >> 2, lc = l & 3;  // staging: row-in-16, 16B chunk

  f32x4 acc[2][4] = {};
  u16* As = smem;          // [32][32]
  u16* Bs = smem + 1024;   // [256][32]
  const u16* arow = A + (size_t)n0 * 256;

#pragma unroll
  for (int kt = 0; kt < 256; kt += 32) {
    __syncthreads();
    if (w < 2) {
      int row = w * 16 + sr;  // 0..31
      union { uint4 u; u16 s[8]; } v, o;
      v.u = *(const uint4*)(arow + (size_t)row * 256 + kt + lc * 8);
      int cb = kt + lc * 8;
#pragma unroll
      for (int j = 0; j < 8; ++j) {
        float f = fmaf(b2f(v.s[j]), scA[cb + j], shA[cb + j]);
        o.s[j] = f2b(fmaxf(f, 0.0f));
      }
      *(uint4*)(As + row * 32 + lc * 8) = o.u;
    }
#pragma unroll
    for (int r = 0; r < 4; ++r) {
      int row = r * 64 + w * 16 + sr;  // 0..255
      GLD_LDS16(B + (size_t)row * 256 + kt + lc * 8, Bs + row * 32 + lc * 8);
    }
    __syncthreads();
    bf16x8 af[2], bf[4];
#pragma unroll
    for (int i = 0; i < 2; ++i)
      af[i] = *(const bf16x8*)(As + (i * 16 + m) * 32 + q * 8);
#pragma unroll
    for (int j = 0; j < 4; ++j)
      bf[j] = *(const bf16x8*)(Bs + (w * 64 + j * 16 + m) * 32 + q * 8);
#pragma unroll
    for (int i = 0; i < 2; ++i)
#pragma unroll
      for (int j = 0; j < 4; ++j)
        acc[i][j] =
            __builtin_amdgcn_mfma_f32_16x16x32_bf16(af[i], bf[j], acc[i][j], 0, 0, 0);
  }

  // stats2 per-column sum/sumsq atomics
  {
    int rep = blockIdx.x & (NREP - 1);
#pragma unroll
    for (int j = 0; j < 4; ++j) {
      float s = 0.0f, ss = 0.0f;
#pragma unroll
      for (int i = 0; i < 2; ++i)
#pragma unroll
        for (int reg = 0; reg < 4; ++reg) {
          float v = acc[i][j][reg];
          s += v;
          ss += v * v;
        }
      s += __shfl_down(s, 32); ss += __shfl_down(ss, 32);
      s += __shfl_down(s, 16); ss += __shfl_down(ss, 16);
      if (l < 16) {
        int c = w * 64 + j * 16 + l;
        atomicAdd(&statsOut[rep * 512 + c], s);
        atomicAdd(&statsOut[rep * 512 + 256 + c], ss);
      }
    }
  }

  // bf16 store via 32x256 LDS bounce
  __syncthreads();
#pragma unroll
  for (int i = 0; i < 2; ++i)
#pragma unroll
    for (int reg = 0; reg < 4; ++reg) {
      int row = i * 16 + q * 4 + reg;
#pragma unroll
      for (int j = 0; j < 4; ++j)
        smem[row * 256 + w * 64 + j * 16 + m] = f2b(acc[i][j][reg]);
    }
  __syncthreads();
  int rbase = t >> 5, seg = t & 31;
#pragma unroll
  for (int itr = 0; itr < 4; ++itr) {
    int row = rbase + itr * 8;
    uint4 v = *(const uint4*)(smem + row * 256 + seg * 8);
    *(uint4*)(out + (size_t)(n0 + row) * 256 + seg * 8) = v;
  }
}

// ---------------------------------------------------------------------------
// BN2 + ReLU + transpose h2(bf16, B*N x 256) -> out fp32 (B,256,N).
// 64x64 tiles (grid 4096): uint2 loads, float4 stores, [64][65] fp32 tile.
// ---------------------------------------------------------------------------
__global__ __launch_bounds__(256) void bn2t_kernel(
    const u16* __restrict__ h2, const float* __restrict__ statsR,
    const float* __restrict__ gamma, const float* __restrict__ beta,
    float* __restrict__ out) {
  __shared__ float tile[64][65];
  __shared__ float sS[64], sH[64];
  int t = threadIdx.x;
  int n0 = blockIdx.x * 64, c0 = blockIdx.y * 64, b = blockIdx.z;
  if (t < 64) {
    int c = c0 + t;
    float s = 0.0f, qq = 0.0f;
#pragma unroll
    for (int r = 0; r < NREP; ++r) {
      s += statsR[r * 512 + c];
      qq += statsR[r * 512 + 256 + c];
    }
    float mean = s * INV_CNT;
    float var = qq * INV_CNT - mean * mean;
    float sc = rsqrtf(var + EPSV) * gamma[c];
    sS[t] = sc;
    sH[t] = beta[c] - mean * sc;
  }
  __syncthreads();
  int tx = t & 15, ty = t >> 4;  // load: tx = ch-quad, ty = row-in-16
#pragma unroll
  for (int i = 0; i < 4; ++i) {
    int n = ty + i * 16;
    uint2 v = *(const uint2*)(h2 + ((size_t)b * NN + n0 + n) * 256 + c0 + tx * 4);
    int c = tx * 4;
    tile[n][c + 0] = fmaxf(fmaf(b2f((u16)(v.x & 0xffff)), sS[c + 0], sH[c + 0]), 0.0f);
    tile[n][c + 1] = fmaxf(fmaf(b2f((u16)(v.x >> 16)),    sS[c + 1], sH[c + 1]), 0.0f);
    tile[n][c + 2] = fmaxf(fmaf(b2f((u16)(v.y & 0xffff)), sS[c + 2], sH[c + 2]), 0.0f);
    tile[n][c + 3] = fmaxf(fmaf(b2f((u16)(v.y >> 16)),    sS[c + 3], sH[c + 3]), 0.0f);
  }
  __syncthreads();
#pragma unroll
  for (int i = 0; i < 4; ++i) {
    int c = ty + i * 16;
    int nq = tx * 4;
    float4 o4 = make_float4(tile[nq + 0][c], tile[nq + 1][c],
                            tile[nq + 2][c], tile[nq + 3][c]);
    *(float4*)(out + ((size_t)(b * 256 + c0 + c)) * NN + n0 + nq) = o4;
  }
}

// ---------------------------------------------------------------------------
// ws layout (bytes):
//   0        stats1R   65536   (32 replicas x 512 floats)
//   65536    stats2R   65536
//   131072   W1b       196608
//   327680   W2b       131072
//   458752   p2t       8388608
//   8847360  p1t       16777216
//   25624576 G(bf16)   8388608
//   34013184 h2b       33554432
//   67567616 pd        4194304
//   71761920 pi        4194304   -> ends ~76 MB
// h1b (bf16) lives in d_out; gemm2 reads it (BN1 fused), bn2t overwrites.
// ---------------------------------------------------------------------------
extern "C" void kernel_launch(void* const* d_in, const int* in_sizes, int n_in,
                              void* d_out, int out_size, void* d_ws,
                              size_t ws_size, hipStream_t stream) {
  const float* xyz1    = (const float*)d_in[0];
  const float* xyz2    = (const float*)d_in[1];
  const float* points1 = (const float*)d_in[2];
  const float* points2 = (const float*)d_in[3];
  const float* W1      = (const float*)d_in[4];
  const float* gamma1  = (const float*)d_in[5];
  const float* beta1   = (const float*)d_in[6];
  const float* W2      = (const float*)d_in[7];
  const float* gamma2  = (const float*)d_in[8];
  const float* beta2   = (const float*)d_in[9];

  char* ws = (char*)d_ws;
  float* stats1R = (float*)(ws + 0);
  float* stats2R = (float*)(ws + 65536);
  u16*   W1b     = (u16*)(ws + 131072);
  u16*   W2b     = (u16*)(ws + 327680);
  u16*   p2t     = (u16*)(ws + 458752);
  u16*   p1t     = (u16*)(ws + 8847360);
  u16*   G       = (u16*)(ws + 25624576);
  u16*   h2b     = (u16*)(ws + 34013184);
  float* pd      = (float*)(ws + 67567616);
  int*   pi      = (int*)(ws + 71761920);
  u16*   h1b     = (u16*)d_out;
  float* out     = (float*)d_out;

  // 1 dispatch: knn (1024 blocks) + W casts + stats zero + transpose-casts
  prep_kernel<<<7840, 256, 0, stream>>>(xyz1, xyz2, pd, pi, points1, points2,
                                        p1t, p2t, W1, W2, W1b, W2b, stats1R);
  // G = p2^T * W1[:, 0:256]^T (bf16 out), XCD-swizzled: batch b on XCD b/2
  gemm_mfma<256, 8, true><<<dim3(128, 2), 256, 0, stream>>>(p2t, 256, W1b, 384,
                                                            G);
  // h1 = p1t * W1[:, 256:384]^T + interp(G); 32x256 tile, 8 blocks/CU
  gemm1_32<<<2048, 256, 0, stream>>>(p1t, W1b + 256, h1b, G, pd, pi, stats1R);
  // h2 = relu(BN1(h1)) * W2^T, 32x256 tile, 8 blocks/CU
  gemm2_32<<<2048, 256, 0, stream>>>(h1b, W2b, h2b, stats2R, stats1R, gamma1,
                                     beta1);
  // BN2 + ReLU + transpose, 64x64 vectorized tiles
  bn2t_kernel<<<dim3(64, 4, 16), 256, 0, stream>>>(h2b, stats2R, gamma2,
                                                   beta2, out);
}

// Round 11
// 209.674 us; speedup vs baseline: 1.0620x; 1.0620x over previous
//
#include <hip/hip_runtime.h>

typedef unsigned short u16;
typedef unsigned int u32;

#define BB 16
#define NN 4096
#define MM 1024
#define C1V 128
#define C2V 256
#define EPSV 1e-5f
#define INV_CNT (1.0f/65536.0f)
#define NREP 32  // stats atomic replicas

typedef __attribute__((ext_vector_type(8))) short bf16x8;
typedef __attribute__((ext_vector_type(4))) float f32x4;

static __device__ __forceinline__ u16 f2b(float f) {
  u32 u = __float_as_uint(f);
  u32 r = (u + 0x7FFFu + ((u >> 16) & 1u)) >> 16;
  return (u16)r;
}
static __device__ __forceinline__ float b2f(u16 s) {
  return __uint_as_float(((u32)s) << 16);
}

#define GLD_LDS16(gp, lp)                                                      \
  __builtin_amdgcn_global_load_lds(                                            \
      (const __attribute__((address_space(1))) void*)(gp),                     \
      (__attribute__((address_space(3))) void*)(lp), 16, 0, 0)

// ---------------------------------------------------------------------------
// Mega-prep kernel.
//   blocks [0,1024)       : 3-NN partials, 1 query/thread (256-eval chains)
//   blocks [1024,1664)    : W1/W2 fp32->bf16 cast
//   blocks [1664,1696)    : zero the 128KB stats replica region
//   blocks [1696,3744)    : transpose-cast points2 -> p2t (64c x 32p tiles)
//   blocks [3744,7840)    : transpose-cast points1 -> p1t (64c x 32p tiles)
// NOTE (journal): do NOT replace the cndmask running-min chains with
// __builtin_amdgcn_fmed3f — two rounds failed correctness that way (R6/R7).
// ---------------------------------------------------------------------------
__device__ __forceinline__ void tcast_tile64(const float* __restrict__ in,
                                             u16* __restrict__ out, int C,
                                             int P, int p0, int c0, int b,
                                             float (*tile)[33]) {
  int tx = threadIdx.x & 31, ty = threadIdx.x >> 5;
  const float* ib = in + (size_t)b * C * P;
  u16* ob = out + (size_t)b * P * C;
#pragma unroll
  for (int i = 0; i < 8; ++i)
    tile[ty + i * 8][tx] = ib[(size_t)(c0 + ty + i * 8) * P + p0 + tx];
  __syncthreads();
#pragma unroll
  for (int i = 0; i < 4; ++i) {
    int p = ty + i * 8;
    u32 v = (u32)f2b(tile[tx * 2][p]) | ((u32)f2b(tile[tx * 2 + 1][p]) << 16);
    *(u32*)&ob[(size_t)(p0 + p) * C + c0 + tx * 2] = v;
  }
}

__global__ __launch_bounds__(256) void prep_kernel(
    const float* __restrict__ xyz1, const float* __restrict__ xyz2,
    float* __restrict__ pd, int* __restrict__ pi,
    const float* __restrict__ points1, const float* __restrict__ points2,
    u16* __restrict__ p1t, u16* __restrict__ p2t,
    const float* __restrict__ W1, const float* __restrict__ W2,
    u16* __restrict__ W1b, u16* __restrict__ W2b,
    float* __restrict__ statsZero) {
  __shared__ float4 cand[256];
  __shared__ float tile[64][33];
  int bx = blockIdx.x;
  int t = threadIdx.x;

  if (bx < 1024) {
    // ---- 3-NN partials: block = (batch b, qtile of 256, chunk c) ----
    int c = bx & 3;
    int qt = (bx >> 2) & 15;
    int b = bx >> 6;
    const float* x2b = xyz2 + b * 3 * MM;
    {
      float x = x2b[c * 256 + t];
      float y = x2b[MM + c * 256 + t];
      float z = x2b[2 * MM + c * 256 + t];
      cand[t] = make_float4(x, y, z, x * x + y * y + z * z);
    }
    __syncthreads();
    const float* x1b = xyz1 + b * 3 * NN;
    int n = qt * 256 + t;
    float px = x1b[n], py = x1b[NN + n], pz = x1b[2 * NN + n];
    const float INF = 3.4e38f;
    float k0 = INF, k1 = INF, k2 = INF;
    int j0 = 0, j1 = 0, j2 = 0;
#pragma unroll 8
    for (int m = 0; m < 256; ++m) {
      float4 cd = cand[m];
      float dot = fmaf(px, cd.x, fmaf(py, cd.y, pz * cd.z));
      float key = fmaf(-2.0f, dot, cd.w);
      bool c0 = key < k0, c1 = key < k1, c2 = key < k2;
      k2 = c1 ? k1 : (c2 ? key : k2);
      j2 = c1 ? j1 : (c2 ? m : j2);
      k1 = c0 ? k0 : (c1 ? key : k1);
      j1 = c0 ? j0 : (c1 ? m : j1);
      k0 = c0 ? key : k0;
      j0 = c0 ? m : j0;
    }
    float pn = px * px + py * py + pz * pz;
    int gq = b * NN + n;
    int base = c << 8;
    ((float4*)pd)[(size_t)c * 65536 + gq] =
        make_float4(fmaxf(k0 + pn, 1e-10f), fmaxf(k1 + pn, 1e-10f),
                    fmaxf(k2 + pn, 1e-10f), 0.0f);
    ((int4*)pi)[(size_t)c * 65536 + gq] =
        make_int4(base + j0, base + j1, base + j2, 0);
  } else if (bx < 1664) {
    // ---- weight casts ----
    int i = (bx - 1024) * 256 + t;
    if (i < 98304) W1b[i] = f2b(W1[i]);
    else if (i < 163840) W2b[i - 98304] = f2b(W2[i - 98304]);
  } else if (bx < 1696) {
    // ---- zero stats replicas: 32 blocks x 256 threads x 16B = 131072 B ----
    ((float4*)statsZero)[(bx - 1664) * 256 + t] =
        make_float4(0.f, 0.f, 0.f, 0.f);
  } else if (bx < 3744) {
    // ---- points2 transpose-cast: P=1024 (32 ptiles), C=256 (4 ctiles) ----
    int local = bx - 1696;
    int pt = local & 31, ct = (local >> 5) & 3, b = local >> 7;
    tcast_tile64(points2, p2t, C2V, MM, pt * 32, ct * 64, b, tile);
  } else {
    // ---- points1 transpose-cast: P=4096 (128 ptiles), C=128 (2 ctiles) ----
    int local = bx - 3744;
    int pt = local & 127, ct = (local >> 7) & 1, b = local >> 8;
    tcast_tile64(points1, p1t, C1V, NN, pt * 32, ct * 64, b, tile);
  }
}

// ---------------------------------------------------------------------------
// gemm1f: h1 = [interp(p2t) | p1t] * W1^T, K=384, 64x256 tile, grid 1024.
//   The G-GEMM dispatch is ELIMINATED by linearity:
//   interp(p2 * W1a^T) == interp(p2) * W1a^T. The A-tile for k<256 is
//   gather+interp of 3 p2t rows (computed in staging, bf16-rounded once);
//   for k>=256 it is p1t via global_load_lds. B = full W1 (ldb 384).
//   Interp-staged LDS writes are linear in t (addr = t*16): conflict-free.
//   No interp epilogue. stats1 atomics + bf16 store via LDS bounce.
// ---------------------------------------------------------------------------
__global__ __launch_bounds__(256) void gemm1f(
    const u16* __restrict__ p1t, const u16* __restrict__ W1b,
    u16* __restrict__ out, const u16* __restrict__ p2t,
    const float* __restrict__ pd, const int* __restrict__ pi,
    float* __restrict__ statsOut) {
  __shared__ __align__(16) u16 smem[16384];  // K: As 4KB | Bs 16KB; bounce 32KB
  __shared__ float wsh[64][3];
  __shared__ int ish[64][3];
  int t = threadIdx.x;
  int w = t >> 6, l = t & 63;
  int p = blockIdx.x;
  int batch = ((p & 7) << 1) | ((p >> 3) & 1);
  int nt = p >> 4;                  // 0..63
  int n0 = batch * NN + nt * 64;    // global row

  // ---- 3-NN merge preamble (once per row) ----
  if (t < 64) {
    int gq = n0 + t;
    float4 d0 = ((const float4*)pd)[gq];
    int4 ii0 = ((const int4*)pi)[gq];
    float a0 = d0.x, a1 = d0.y, a2 = d0.z;
    int b0 = ii0.x, b1 = ii0.y, b2 = ii0.z;
#pragma unroll
    for (int c = 1; c < 4; ++c) {
      float4 dc = ((const float4*)pd)[(size_t)c * 65536 + gq];
      int4 ic = ((const int4*)pi)[(size_t)c * 65536 + gq];
      float kv[3] = {dc.x, dc.y, dc.z};
      int jv[3] = {ic.x, ic.y, ic.z};
#pragma unroll
      for (int j = 0; j < 3; ++j) {
        float key = kv[j];
        int idx = jv[j];
        bool c0 = key < a0, c1 = key < a1, c2 = key < a2;
        a2 = c1 ? a1 : (c2 ? key : a2);
        b2 = c1 ? b1 : (c2 ? idx : b2);
        a1 = c0 ? a0 : (c1 ? key : a1);
        b1 = c0 ? b0 : (c1 ? idx : b1);
        a0 = c0 ? key : a0;
        b0 = c0 ? idx : b0;
      }
    }
    float v0 = 1.0f / a0, v1 = 1.0f / a1, v2 = 1.0f / a2;
    float s = 1.0f / (v0 + v1 + v2);
    wsh[t][0] = v0 * s; wsh[t][1] = v1 * s; wsh[t][2] = v2 * s;
    ish[t][0] = b0;     ish[t][1] = b1;     ish[t][2] = b2;
  }
  __syncthreads();  // wsh/ish visible to all before staging hoists

  int q = l >> 4, m = l & 15;   // mfma lane decomposition
  int sr = l >> 2, lc = l & 3;  // GLD staging: row-in-16, 16B chunk
  int irow = t >> 2, iseg = t & 3;  // interp staging: row, 16B seg

  // Hoist per-thread interp gather bases/weights (valid post-barrier).
  int b = n0 >> 12;
  float iw0 = wsh[irow][0], iw1 = wsh[irow][1], iw2 = wsh[irow][2];
  const u16* g0b = p2t + ((size_t)(b * 1024 + ish[irow][0])) * 256 + iseg * 8;
  const u16* g1b = p2t + ((size_t)(b * 1024 + ish[irow][1])) * 256 + iseg * 8;
  const u16* g2b = p2t + ((size_t)(b * 1024 + ish[irow][2])) * 256 + iseg * 8;

  f32x4 acc[4][4] = {};
  u16* As = smem;          // [64][32]
  u16* Bs = smem + 2048;   // [256][32]
  const u16* arow = p1t + (size_t)n0 * 128;

#pragma unroll
  for (int kt = 0; kt < 384; kt += 32) {
    __syncthreads();
    if (kt < 256) {
      // interp-staged A-tile: 3-row gather, fp32 interp, bf16 pack
      bf16x8 v0 = *(const bf16x8*)(g0b + kt);
      bf16x8 v1 = *(const bf16x8*)(g1b + kt);
      bf16x8 v2 = *(const bf16x8*)(g2b + kt);
      union { uint4 u; u16 s[8]; } o;
#pragma unroll
      for (int e = 0; e < 8; ++e) {
        float f = iw0 * b2f((u16)v0[e]) + iw1 * b2f((u16)v1[e]) +
                  iw2 * b2f((u16)v2[e]);
        o.s[e] = f2b(f);
      }
      *(uint4*)(As + t * 8) = o.u;  // addr = t*16B: linear, conflict-free
    } else {
      int row = w * 16 + sr;  // 0..63
      GLD_LDS16(arow + (size_t)row * 128 + (kt - 256) + lc * 8,
                As + row * 32 + lc * 8);
    }
#pragma unroll
    for (int r = 0; r < 4; ++r) {
      int row2 = r * 64 + w * 16 + sr;  // 0..255 output channels
      GLD_LDS16(W1b + (size_t)row2 * 384 + kt + lc * 8,
                Bs + row2 * 32 + lc * 8);
    }
    __syncthreads();
    bf16x8 af[4], bf[4];
#pragma unroll
    for (int i = 0; i < 4; ++i)
      af[i] = *(const bf16x8*)(As + (i * 16 + m) * 32 + q * 8);
#pragma unroll
    for (int j = 0; j < 4; ++j)
      bf[j] = *(const bf16x8*)(Bs + (w * 64 + j * 16 + m) * 32 + q * 8);
#pragma unroll
    for (int i = 0; i < 4; ++i)
#pragma unroll
      for (int j = 0; j < 4; ++j)
        acc[i][j] =
            __builtin_amdgcn_mfma_f32_16x16x32_bf16(af[i], bf[j], acc[i][j], 0, 0, 0);
  }

  // ---- stats1 per-column sum/sumsq atomics ----
  {
    int rep = blockIdx.x & (NREP - 1);
#pragma unroll
    for (int j = 0; j < 4; ++j) {
      float s = 0.0f, ss = 0.0f;
#pragma unroll
      for (int i = 0; i < 4; ++i)
#pragma unroll
        for (int reg = 0; reg < 4; ++reg) {
          float v = acc[i][j][reg];
          s += v;
          ss += v * v;
        }
      s += __shfl_down(s, 32); ss += __shfl_down(ss, 32);
      s += __shfl_down(s, 16); ss += __shfl_down(ss, 16);
      if (l < 16) {
        int c = w * 64 + j * 16 + l;
        atomicAdd(&statsOut[rep * 512 + c], s);
        atomicAdd(&statsOut[rep * 512 + 256 + c], ss);
      }
    }
  }

  // ---- bf16 store via 64x256 LDS bounce ----
  __syncthreads();
#pragma unroll
  for (int i = 0; i < 4; ++i)
#pragma unroll
    for (int reg = 0; reg < 4; ++reg) {
      int row = i * 16 + q * 4 + reg;
#pragma unroll
      for (int j = 0; j < 4; ++j)
        smem[row * 256 + w * 64 + j * 16 + m] = f2b(acc[i][j][reg]);
    }
  __syncthreads();
  int rbase = t >> 5, seg = t & 31;
#pragma unroll
  for (int itr = 0; itr < 8; ++itr) {
    int row = rbase + itr * 8;
    uint4 v = *(const uint4*)(smem + row * 256 + seg * 8);
    *(uint4*)(out + (size_t)(n0 + row) * 256 + seg * 8) = v;
  }
}

// ---------------------------------------------------------------------------
// gemm2_64: h2 = relu(BN1(h1)) * W2^T, 64x256 tile, grid (1024,1).
//   2-PHASE K-loop (R9, best measured): B staged via GLD_LDS into the other
//   buffer before compute; A (reg-staged, BN1-fused) uses the T14 split.
// ---------------------------------------------------------------------------
__global__ __launch_bounds__(256) void gemm2_64(
    const u16* __restrict__ A, const u16* __restrict__ B,
    u16* __restrict__ out, float* __restrict__ statsOut,
    const float* __restrict__ statsInR, const float* __restrict__ gamma,
    const float* __restrict__ beta) {
  __shared__ __align__(16) u16 smem[20480];  // 40KB
  __shared__ float scA[256], shA[256];
  int t = threadIdx.x;
  int w = t >> 6, l = t & 63;
  int n0 = blockIdx.x * 64;

  // BN1 scale/shift from stats1 replicas (plain cached loads)
  {
    float s = 0.0f, qq = 0.0f;
#pragma unroll
    for (int r = 0; r < NREP; ++r) {
      s += statsInR[r * 512 + t];
      qq += statsInR[r * 512 + 256 + t];
    }
    float mean = s * INV_CNT;
    float var = qq * INV_CNT - mean * mean;
    float sc = rsqrtf(var + EPSV) * gamma[t];
    scA[t] = sc;
    shA[t] = beta[t] - mean * sc;
  }
  __syncthreads();  // scA/shA ready before first staging use

  int q = l >> 4, m = l & 15;   // mfma lane decomposition
  int sr = l >> 2, lc = l & 3;  // staging: row-in-16, 16B chunk

  f32x4 acc[4][4] = {};
  u16* Asb[2] = {smem, smem + 2048};           // [64][32] each
  u16* Bsb[2] = {smem + 4096, smem + 12288};   // [256][32] each
  const u16* arow = A + (size_t)n0 * 256;
  int arowoff = (w * 16 + sr) * 256 + lc * 8;
  int aldsoff = (w * 16 + sr) * 32 + lc * 8;

  // ---- prologue: stage tile 0 (A: load+BN1+write; B: GLD_LDS) ----
  {
    union { uint4 u; u16 s[8]; } v, o;
    v.u = *(const uint4*)(arow + arowoff);
#pragma unroll
    for (int r = 0; r < 4; ++r) {
      int row2 = r * 64 + w * 16 + sr;
      GLD_LDS16(B + (size_t)row2 * 256 + lc * 8, Bsb[0] + row2 * 32 + lc * 8);
    }
    int cb = lc * 8;
#pragma unroll
    for (int j = 0; j < 8; ++j) {
      float f = fmaf(b2f(v.s[j]), scA[cb + j], shA[cb + j]);
      o.s[j] = f2b(fmaxf(f, 0.0f));
    }
    *(uint4*)(Asb[0] + aldsoff) = o.u;
  }
  __syncthreads();

#pragma unroll
  for (int it = 0; it < 8; ++it) {
    const int cur = it & 1, nxt = cur ^ 1;
    union { uint4 u; u16 s[8]; } an;
    if (it < 7) {
      int kt = (it + 1) * 32;
      an.u = *(const uint4*)(arow + arowoff + kt);  // issue early (T14)
#pragma unroll
      for (int r = 0; r < 4; ++r) {
        int row2 = r * 64 + w * 16 + sr;
        GLD_LDS16(B + (size_t)row2 * 256 + kt + lc * 8,
                  Bsb[nxt] + row2 * 32 + lc * 8);
      }
    }
    bf16x8 af[4], bf[4];
#pragma unroll
    for (int i = 0; i < 4; ++i)
      af[i] = *(const bf16x8*)(Asb[cur] + (i * 16 + m) * 32 + q * 8);
#pragma unroll
    for (int j = 0; j < 4; ++j)
      bf[j] = *(const bf16x8*)(Bsb[cur] + (w * 64 + j * 16 + m) * 32 + q * 8);
#pragma unroll
    for (int i = 0; i < 4; ++i)
#pragma unroll
      for (int j = 0; j < 4; ++j)
        acc[i][j] =
            __builtin_amdgcn_mfma_f32_16x16x32_bf16(af[i], bf[j], acc[i][j], 0, 0, 0);
    if (it < 7) {
      int kt = (it + 1) * 32;
      int cb = kt + lc * 8;
      union { uint4 u; u16 s[8]; } o;
#pragma unroll
      for (int j = 0; j < 8; ++j) {
        float f = fmaf(b2f(an.s[j]), scA[cb + j], shA[cb + j]);
        o.s[j] = f2b(fmaxf(f, 0.0f));
      }
      *(uint4*)(Asb[nxt] + aldsoff) = o.u;
    }
    __syncthreads();
  }

  // stats2 per-column sum/sumsq atomics
  {
    int rep = blockIdx.x & (NREP - 1);
#pragma unroll
    for (int j = 0; j < 4; ++j) {
      float s = 0.0f, ss = 0.0f;
#pragma unroll
      for (int i = 0; i < 4; ++i)
#pragma unroll
        for (int reg = 0; reg < 4; ++reg) {
          float v = acc[i][j][reg];
          s += v;
          ss += v * v;
        }
      s += __shfl_down(s, 32); ss += __shfl_down(ss, 32);
      s += __shfl_down(s, 16); ss += __shfl_down(ss, 16);
      if (l < 16) {
        int c = w * 64 + j * 16 + l;
        atomicAdd(&statsOut[rep * 512 + c], s);
        atomicAdd(&statsOut[rep * 512 + 256 + c], ss);
      }
    }
  }

  // bf16 store via 64x256 LDS bounce
  __syncthreads();
#pragma unroll
  for (int i = 0; i < 4; ++i)
#pragma unroll
    for (int reg = 0; reg < 4; ++reg) {
      int row = i * 16 + q * 4 + reg;
#pragma unroll
      for (int j = 0; j < 4; ++j)
        smem[row * 256 + w * 64 + j * 16 + m] = f2b(acc[i][j][reg]);
    }
  __syncthreads();
  int rbase = t >> 5, seg = t & 31;
#pragma unroll
  for (int itr = 0; itr < 8; ++itr) {
    int row = rbase + itr * 8;
    uint4 v = *(const uint4*)(smem + row * 256 + seg * 8);
    *(uint4*)(out + (size_t)(n0 + row) * 256 + seg * 8) = v;
  }
}

// ---------------------------------------------------------------------------
// BN2 + ReLU + transpose h2(bf16, B*N x 256) -> out fp32 (B,256,N).
// 64x64 tiles (grid 4096): uint2 loads, float4 stores, [64][65] fp32 tile.
// ---------------------------------------------------------------------------
__global__ __launch_bounds__(256) void bn2t_kernel(
    const u16* __restrict__ h2, const float* __restrict__ statsR,
    const float* __restrict__ gamma, const float* __restrict__ beta,
    float* __restrict__ out) {
  __shared__ float tile[64][65];
  __shared__ float sS[64], sH[64];
  int t = threadIdx.x;
  int n0 = blockIdx.x * 64, c0 = blockIdx.y * 64, b = blockIdx.z;
  if (t < 64) {
    int c = c0 + t;
    float s = 0.0f, qq = 0.0f;
#pragma unroll
    for (int r = 0; r < NREP; ++r) {
      s += statsR[r * 512 + c];
      qq += statsR[r * 512 + 256 + c];
    }
    float mean = s * INV_CNT;
    float var = qq * INV_CNT - mean * mean;
    float sc = rsqrtf(var + EPSV) * gamma[c];
    sS[t] = sc;
    sH[t] = beta[c] - mean * sc;
  }
  __syncthreads();
  int tx = t & 15, ty = t >> 4;  // load: tx = ch-quad, ty = row-in-16
#pragma unroll
  for (int i = 0; i < 4; ++i) {
    int n = ty + i * 16;
    uint2 v = *(const uint2*)(h2 + ((size_t)b * NN + n0 + n) * 256 + c0 + tx * 4);
    int c = tx * 4;
    tile[n][c + 0] = fmaxf(fmaf(b2f((u16)(v.x & 0xffff)), sS[c + 0], sH[c + 0]), 0.0f);
    tile[n][c + 1] = fmaxf(fmaf(b2f((u16)(v.x >> 16)),    sS[c + 1], sH[c + 1]), 0.0f);
    tile[n][c + 2] = fmaxf(fmaf(b2f((u16)(v.y & 0xffff)), sS[c + 2], sH[c + 2]), 0.0f);
    tile[n][c + 3] = fmaxf(fmaf(b2f((u16)(v.y >> 16)),    sS[c + 3], sH[c + 3]), 0.0f);
  }
  __syncthreads();
#pragma unroll
  for (int i = 0; i < 4; ++i) {
    int c = ty + i * 16;
    int nq = tx * 4;
    float4 o4 = make_float4(tile[nq + 0][c], tile[nq + 1][c],
                            tile[nq + 2][c], tile[nq + 3][c]);
    *(float4*)(out + ((size_t)(b * 256 + c0 + c)) * NN + n0 + nq) = o4;
  }
}

// ---------------------------------------------------------------------------
// ws layout (bytes):
//   0        stats1R   65536   (32 replicas x 512 floats)
//   65536    stats2R   65536
//   131072   W1b       196608
//   327680   W2b       131072
//   458752   p2t       8388608
//   8847360  p1t       16777216
//   25624576 (free; G eliminated — interp fused into gemm1f staging)
//   34013184 h2b       33554432
//   67567616 pd        4194304
//   71761920 pi        4194304   -> ends ~76 MB
// h1b (bf16) lives in d_out; gemm2 reads it (BN1 fused), bn2t overwrites.
// ---------------------------------------------------------------------------
extern "C" void kernel_launch(void* const* d_in, const int* in_sizes, int n_in,
                              void* d_out, int out_size, void* d_ws,
                              size_t ws_size, hipStream_t stream) {
  const float* xyz1    = (const float*)d_in[0];
  const float* xyz2    = (const float*)d_in[1];
  const float* points1 = (const float*)d_in[2];
  const float* points2 = (const float*)d_in[3];
  const float* W1      = (const float*)d_in[4];
  const float* gamma1  = (const float*)d_in[5];
  const float* beta1   = (const float*)d_in[6];
  const float* W2      = (const float*)d_in[7];
  const float* gamma2  = (const float*)d_in[8];
  const float* beta2   = (const float*)d_in[9];

  char* ws = (char*)d_ws;
  float* stats1R = (float*)(ws + 0);
  float* stats2R = (float*)(ws + 65536);
  u16*   W1b     = (u16*)(ws + 131072);
  u16*   W2b     = (u16*)(ws + 327680);
  u16*   p2t     = (u16*)(ws + 458752);
  u16*   p1t     = (u16*)(ws + 8847360);
  u16*   h2b     = (u16*)(ws + 34013184);
  float* pd      = (float*)(ws + 67567616);
  int*   pi      = (int*)(ws + 71761920);
  u16*   h1b     = (u16*)d_out;
  float* out     = (float*)d_out;

  // 1 dispatch: knn (1024 blocks) + W casts + stats zero + transpose-casts
  prep_kernel<<<7840, 256, 0, stream>>>(xyz1, xyz2, pd, pi, points1, points2,
                                        p1t, p2t, W1, W2, W1b, W2b, stats1R);
  // h1 = [interp(p2t) | p1t] * W1^T (K=384); G-GEMM eliminated by linearity
  gemm1f<<<1024, 256, 0, stream>>>(p1t, W1b, h1b, p2t, pd, pi, stats1R);
  // h2 = relu(BN1(h1)) * W2^T, 64x256 tile, 2-phase K-loop + T14 A-split
  gemm2_64<<<1024, 256, 0, stream>>>(h1b, W2b, h2b, stats2R, stats1R, gamma1,
                                     beta1);
  // BN2 + ReLU + transpose, 64x64 vectorized tiles
  bn2t_kernel<<<dim3(64, 4, 16), 256, 0, stream>>>(h2b, stats2R, gamma2,
                                                   beta2, out);
}